// Round 1
// baseline (7800.150 us; speedup 1.0000x reference)
//
#include <hip/hip_runtime.h>

#define SEQ 1024
#define NB  64
#define NI  256
#define NH  256

typedef __bf16 bf16x8 __attribute__((ext_vector_type(8)));
typedef float  f32x4  __attribute__((ext_vector_type(4)));
typedef unsigned short u16;

__device__ __forceinline__ u16 f2bf(float f) {
    unsigned int u = __float_as_uint(f);
    u += 0x7fffu + ((u >> 16) & 1u);
    return (u16)(u >> 16);
}
__device__ __forceinline__ float sigm_(float x) {
    return __builtin_amdgcn_rcpf(1.0f + __builtin_amdgcn_exp2f(-1.4426950408889634f * x));
}
__device__ __forceinline__ float tanh_(float x) {
    return 1.0f - 2.0f * __builtin_amdgcn_rcpf(__builtin_amdgcn_exp2f(2.8853900817779268f * x) + 1.0f);
}

// Persistent scan kernel.
// Grid: 32 WGs = 2 batch-groups (32 rows each) x 16 column-slices (16 h-cols each).
// Each WG holds its W_ih / W_hh slices as MFMA B-fragments in registers.
// Per step: stage x[s] (bf16, swizzled LDS) -> MFMA (x*Wih + m*Whh, f32 acc)
// -> gates via LDS -> elementwise cell -> publish new_m slice -> counter barrier
// (per batch-group, device-scope) -> restage full m.
__global__ __launch_bounds__(256, 1)
void nas_scan(const float* __restrict__ xg, const float* __restrict__ wih,
              const float* __restrict__ whh, float* __restrict__ out,
              unsigned int* cnt, u16* mex)
{
    __shared__ __align__(16) unsigned char xbuf[32 * 512]; // [row][k] bf16, swizzled
    __shared__ __align__(16) unsigned char mbuf[32 * 512]; // [row][k] bf16, swizzled
    __shared__ float gbuf[32 * 132];                       // [row][gate*16+col], pad 4

    const int t    = threadIdx.x;
    const int lane = t & 63;
    const int wave = t >> 6;
    const int fr   = lane & 15;   // MFMA row/col within tile
    const int fq   = lane >> 4;   // MFMA k-group / row-group
    const int g2   = blockIdx.x & 1;   // batch-group: rows g2*32 .. +32
    const int jwg  = blockIdx.x >> 1;  // column slice: h in [jwg*16, jwg*16+16)
    const int c0   = jwg * 16;
    const int Mt   = wave & 1;    // 16-row tile within group
    const int Gh   = wave >> 1;   // gate half: gates Gh*4 .. +3

    const f32x4 fzero = {0.f, 0.f, 0.f, 0.f};

    // ---- gather weight B-fragments into registers (bf16), once ----
    // B-frag (16x16x32): lane holds col = lane&15, k = (lane>>4)*8 + j (j=0..7)
    bf16x8 wfih[4][8], wfhh[4][8];
#pragma unroll
    for (int gi = 0; gi < 4; ++gi) {
        const int g = Gh * 4 + gi;
#pragma unroll
        for (int ks = 0; ks < 8; ++ks) {
            const int kb = ks * 32 + fq * 8;
            bf16x8 a, b;
#pragma unroll
            for (int j = 0; j < 8; ++j) {
                const int idx = ((g * NH) + kb + j) * NH + (c0 + fr);
                a[j] = (__bf16)wih[idx];
                b[j] = (__bf16)whh[idx];
            }
            wfih[gi][ks] = a;
            wfhh[gi][ks] = b;
        }
    }

    // ---- zero m staging (state_m starts at 0) ----
#pragma unroll
    for (int i = 0; i < 4; ++i)
        *(f32x4*)(mbuf + t * 64 + i * 16) = fzero;

    // ---- prefetch x for step 0 ----
    const size_t xstep = (size_t)NB * NI;           // 16384 floats per step
    const float* xrow  = xg + (size_t)g2 * 32 * NI; // batch-group base
    f32x4 xp[8];
#pragma unroll
    for (int i = 0; i < 8; ++i)
        xp[i] = *(const f32x4*)(xrow + i * 1024 + t * 4);

    // per-thread owned output elements: row r_own, cols {2*cp_own, 2*cp_own+1}
    const int r_own  = t >> 3;
    const int cp_own = t & 7;
    float cst0 = 0.0f, cst1 = 0.0f; // state_c, lives in registers

    unsigned int* mycnt = cnt + g2 * 32;

    for (int s = 0; s < SEQ; ++s) {
        // ---- stage x[s] into LDS as bf16 (XOR-swizzled rows) ----
#pragma unroll
        for (int i = 0; i < 8; ++i) {
            const int row = i * 4 + (t >> 6);
            const unsigned off = (unsigned)row * 512u + (unsigned)(t & 63) * 8u;
            unsigned long long pk =
                  (unsigned long long)f2bf(xp[i][0])
                | ((unsigned long long)f2bf(xp[i][1]) << 16)
                | ((unsigned long long)f2bf(xp[i][2]) << 32)
                | ((unsigned long long)f2bf(xp[i][3]) << 48);
            *(unsigned long long*)(xbuf + (off ^ (((unsigned)row & 7u) << 4))) = pk;
        }
        __syncthreads();

        // ---- MFMA: acc[g] = x*Wih[g] + m*Whh[g], f32 accumulate ----
        f32x4 acc[4];
#pragma unroll
        for (int gi = 0; gi < 4; ++gi) acc[gi] = fzero;
        {
            const int arow = Mt * 16 + fr;
            const unsigned abase = (unsigned)arow * 512u + (unsigned)fq * 16u;
            const unsigned aswz  = ((unsigned)arow & 7u) << 4;
#pragma unroll
            for (int ks = 0; ks < 8; ++ks) {
                const unsigned off = (abase + (unsigned)ks * 64u) ^ aswz;
                bf16x8 ax = *(const bf16x8*)(xbuf + off);
                bf16x8 am = *(const bf16x8*)(mbuf + off);
#pragma unroll
                for (int gi = 0; gi < 4; ++gi)
                    acc[gi] = __builtin_amdgcn_mfma_f32_16x16x32_bf16(ax, wfih[gi][ks], acc[gi], 0, 0, 0);
#pragma unroll
                for (int gi = 0; gi < 4; ++gi)
                    acc[gi] = __builtin_amdgcn_mfma_f32_16x16x32_bf16(am, wfhh[gi][ks], acc[gi], 0, 0, 0);
            }
        }

        // ---- write gates to LDS (C-layout: row=(lane>>4)*4+j, col=lane&15) ----
#pragma unroll
        for (int gi = 0; gi < 4; ++gi) {
            const int g = Gh * 4 + gi;
#pragma unroll
            for (int j = 0; j < 4; ++j) {
                const int row = Mt * 16 + fq * 4 + j;
                gbuf[row * 132 + g * 16 + fr] = acc[gi][j];
            }
        }
        __syncthreads();

        // ---- elementwise NAS cell on 2 owned elements ----
        float nm0, nm1;
        {
            float nc[2], nm[2];
#pragma unroll
            for (int e = 0; e < 2; ++e) {
                const int col = cp_own * 2 + e;
                const float* gb = gbuf + r_own * 132 + col;
                const float q0 = gb[0 * 16], q1 = gb[1 * 16], q2 = gb[2 * 16], q3 = gb[3 * 16];
                const float q4 = gb[4 * 16], q5 = gb[5 * 16], q6 = gb[6 * 16], q7 = gb[7 * 16];
                const float l10 = sigm_(q0);
                const float l11 = fmaxf(q1, 0.0f);
                const float l12 = sigm_(q2);
                const float l13 = fmaxf(q3, 0.0f);
                const float l14 = tanh_(q4);
                const float l15 = sigm_(q5);
                const float l16 = tanh_(q6);
                const float l17 = sigm_(q7);
                const float l20 = tanh_(l10 * l11);
                const float l21 = tanh_(l12 + l13);
                const float l22 = tanh_(l14 * l15);
                const float l23 = sigm_(l16 + l17);
                const float cold = (e == 0) ? cst0 : cst1;
                const float l20v = tanh_(l20 + cold);
                const float ncv  = l20v * l21;
                const float l31  = tanh_(l22 + l23);
                nc[e] = ncv;
                nm[e] = tanh_(ncv * l31);
            }
            cst0 = nc[0]; cst1 = nc[1];
            nm0 = nm[0]; nm1 = nm[1];
        }

        if (s == SEQ - 1) {
            // final output: state_c + state_m
            const int obase = (g2 * 32 + r_own) * NH + c0 + cp_own * 2;
            out[obase + 0] = cst0 + nm0;
            out[obase + 1] = cst1 + nm1;
        } else {
            // ---- publish new_m slice (bf16, double-buffered by step parity) ----
            u16* mw = mex + (size_t)(s & 1) * 16384 + (size_t)g2 * 8192;
            const unsigned pkm = (unsigned)f2bf(nm0) | ((unsigned)f2bf(nm1) << 16);
            *(unsigned int*)(mw + r_own * NH + c0 + cp_own * 2) = pkm;

            // per-wave release add: drains this wave's stores, publishes them
            if (lane == 0)
                __hip_atomic_fetch_add(mycnt, 1u, __ATOMIC_RELEASE, __HIP_MEMORY_SCOPE_AGENT);

            // prefetch x[s+1] now so HBM/L3 latency hides under the spin
            const float* xnext = xrow + (size_t)(s + 1) * xstep;
#pragma unroll
            for (int i = 0; i < 8; ++i)
                xp[i] = *(const f32x4*)(xnext + i * 1024 + t * 4);

            // wait for all 16 WGs x 4 waves of this batch-group
            if (t == 0) {
                const unsigned int target = 64u * (unsigned)(s + 1);
                while (__hip_atomic_load(mycnt, __ATOMIC_RELAXED, __HIP_MEMORY_SCOPE_AGENT) < target)
                    __builtin_amdgcn_s_sleep(1);
                __builtin_amdgcn_fence(__ATOMIC_ACQUIRE, "agent");
            }
            __syncthreads();

            // ---- restage full new m into LDS (swizzled) ----
            const u16* ms = mex + (size_t)(s & 1) * 16384 + (size_t)g2 * 8192;
#pragma unroll
            for (int j = 0; j < 4; ++j) {
                const int p   = j * 2048 + t * 8;
                const int row = p >> 8;
                const unsigned off = (unsigned)row * 512u + (unsigned)(p & 255) * 2u;
                f32x4 v = *(const f32x4*)(ms + p);
                *(f32x4*)(mbuf + (off ^ (((unsigned)row & 7u) << 4))) = v;
            }
            // visibility of mbuf writes covered by the loop-top __syncthreads
        }
    }
}

__global__ void nas_init(unsigned int* cnt) {
    cnt[threadIdx.x] = 0u;
}

extern "C" void kernel_launch(void* const* d_in, const int* in_sizes, int n_in,
                              void* d_out, int out_size, void* d_ws, size_t ws_size,
                              hipStream_t stream) {
    (void)in_sizes; (void)n_in; (void)out_size; (void)ws_size;
    const float* x   = (const float*)d_in[0];
    const float* wih = (const float*)d_in[1];
    const float* whh = (const float*)d_in[2];
    float* out = (float*)d_out;

    unsigned int* cnt = (unsigned int*)d_ws;              // 1 KB of counters
    u16* mex = (u16*)((char*)d_ws + 1024);                // 64 KB m exchange (2 parity x 2 group x 32 x 256 bf16)

    nas_init<<<dim3(1), dim3(64), 0, stream>>>(cnt);
    nas_scan<<<dim3(32), dim3(256), 0, stream>>>(x, wih, whh, out, cnt, mex);
}